// Round 16
// baseline (374.904 us; speedup 1.0000x reference)
//
#include <hip/hip_runtime.h>
#include <hip/hip_bf16.h>
#include <math.h>

#define B_SZ 1024
#define NMAX 21
#define NN 441            // 21*21
#define HNF 256
#define TOT_ROWS (B_SZ * NN)   // 451584
#define TILES_PB 14            // 14 tiles of 32 rows per batch (448 >= 441)
#define TROWS 32

typedef short short8 __attribute__((ext_vector_type(8)));
typedef float float4v __attribute__((ext_vector_type(4)));

__device__ __forceinline__ unsigned short f2bf(float x) {
    union { float f; unsigned int u; } v; v.f = x;
    unsigned int r = v.u + 0x7FFFu + ((v.u >> 16) & 1u);   // RNE
    return (unsigned short)(r >> 16);
}

// hardware packed fp32->bf16 (v_cvt_pk_bf16_f32), RNE
__device__ __forceinline__ unsigned pk_bf16(float lo, float hi) {
    __hip_bfloat162 h = __float22bfloat162_rn(float2{lo, hi});
    return *reinterpret_cast<unsigned*>(&h);
}

// fast softplus: max(x,0) + ln2*log2(1 + exp2(-|x|*log2e)), raw v_exp/v_log
__device__ __forceinline__ float softplus_fast(float x) {
    float e = __builtin_amdgcn_exp2f(-fabsf(x) * 1.44269504088896f);
    float lg = __builtin_amdgcn_logf(1.f + e);
    return fmaxf(x, 0.f) + 0.69314718055995f * lg;
}

// fast tanh for x>=0: 1 - 2/(exp2(x*2log2e)+1). v_exp/v_rcp approx (~1e-7).
__device__ __forceinline__ float tanh_fast(float x) {
    float e = __builtin_amdgcn_exp2f(x * 2.8853900817779268f);
    float q = __builtin_amdgcn_rcpf(e + 1.f);
    return fmaf(-2.f, q, 1.f);
}

// ---------------------------------------------------------------------------
// Pack W1 into MFMA B-fragment order as bf16 (+ zero emb, folded in).
// ---------------------------------------------------------------------------
__global__ __launch_bounds__(256) void pack_w1(const float* __restrict__ W1,
                                               short* __restrict__ B0p,
                                               float* __restrict__ emb)
{
    int id = blockIdx.x * 256 + threadIdx.x;   // 0..65535
    int j = id & 7, l = (id >> 3) & 63, f = (id >> 9) & 15, s = id >> 13;
    int k = s * 32 + ((l >> 4) << 3) + j;
    int c = (f << 4) + (l & 15);
    B0p[id] = (short)f2bf(W1[k * HNF + c]);
    #pragma unroll
    for (int e = 0; e < 4; e++)
        emb[(size_t)e * 65536 + id] = 0.f;     // 4*65536 = 1024*256
}

// ---------------------------------------------------------------------------
// Kernel 1 (R16): ZERO-STAGING direct-register MFMA. 14336 blocks x 256
// threads (4 waves); tile 32x256, wave w owns n-frags 4w..4w+3, all 32 rows.
// The 16x16x32 A-fragment is 8 CONTIGUOUS k-elements per lane (lane l: row
// l&15 (+m*16), k = kk*32 + (l>>4)*8 + j) = 32 contiguous bytes at a 128B-
// aligned offset -> loaded straight from global (2 x float4), converted via
// v_cvt_pk_bf16_f32, fed to MFMA. No LDS for A, no DMA, no vmcnt, NO
// barriers until the epilogue reduce. Waves are fully independent streams
// (no convoying); A re-read 4x/block is L2-absorbed. LDS = 1KB (red only).
// ---------------------------------------------------------------------------
__global__ __launch_bounds__(256, 4) void fused_mlp_bf16(
    const float* __restrict__ gnn, const short* __restrict__ B0p,
    const float* __restrict__ b1, const float* __restrict__ W2,
    const float* __restrict__ b2,
    float* __restrict__ Dreg, float* __restrict__ Wreg, float* __restrict__ emb)
{
    __shared__ float red0[4][32];
    __shared__ float red1[4][32];

    const int t = threadIdx.x;
    const int w = t >> 6, l = t & 63;
    const int batch = blockIdx.x / TILES_PB;
    const int tile  = blockIdx.x % TILES_PB;
    const long row0 = (long)batch * NN + (long)tile * TROWS;
    const int vr = (tile == TILES_PB - 1) ? (NN - (TILES_PB - 1) * TROWS) : TROWS; // 25 or 32

    // fragment decode
    const int frow = l & 15;
    const int fk   = l >> 4;

    // per-lane A row pointers for m=0,1 (clamped at global end)
    long ar0 = row0 + frow;        if (ar0 >= (long)TOT_ROWS) ar0 = TOT_ROWS - 1;
    long ar1 = row0 + 16 + frow;   if (ar1 >= (long)TOT_ROWS) ar1 = TOT_ROWS - 1;
    const float* ap0 = gnn + ar0 * HNF + (fk << 3);
    const float* ap1 = gnn + ar1 * HNF + (fk << 3);

    // ---- MFMA loop: 8 k-steps x (2m x 4n) per wave, direct global A ----
    float4v acc[2][4];
    #pragma unroll
    for (int m = 0; m < 2; m++)
        #pragma unroll
        for (int n = 0; n < 4; n++)
            acc[m][n] = (float4v){0.f, 0.f, 0.f, 0.f};

    #pragma unroll 2
    for (int kk = 0; kk < 8; ++kk) {
        // A fragments: 2 x (2 x float4) contiguous loads, cvt to bf16
        float4 a00 = *(const float4*)(ap0 + (kk << 5));
        float4 a01 = *(const float4*)(ap0 + (kk << 5) + 4);
        float4 a10 = *(const float4*)(ap1 + (kk << 5));
        float4 a11 = *(const float4*)(ap1 + (kk << 5) + 4);
        // B fragments from L2-resident packed W1
        short8 bf[4];
        #pragma unroll
        for (int n = 0; n < 4; n++) {
            int nf = (w << 2) + n;
            size_t off = (size_t)((((kk << 4) + nf) << 6) | l) << 3;
            bf[n] = *(const short8*)(B0p + off);
        }
        unsigned af0[4], af1[4];
        af0[0] = pk_bf16(a00.x, a00.y); af0[1] = pk_bf16(a00.z, a00.w);
        af0[2] = pk_bf16(a01.x, a01.y); af0[3] = pk_bf16(a01.z, a01.w);
        af1[0] = pk_bf16(a10.x, a10.y); af1[1] = pk_bf16(a10.z, a10.w);
        af1[2] = pk_bf16(a11.x, a11.y); af1[3] = pk_bf16(a11.z, a11.w);
        short8 af[2];
        af[0] = *(short8*)af0;
        af[1] = *(short8*)af1;
        #pragma unroll
        for (int m = 0; m < 2; m++)
            #pragma unroll
            for (int n = 0; n < 4; n++)
                acc[m][n] = __builtin_amdgcn_mfma_f32_16x16x32_bf16(af[m], bf[n], acc[m][n], 0, 0, 0);
    }

    // ---- epilogue: bias+relu, e2 row-dots, emb partials ----
    // C frag: col = (4w+n)*16 + (l&15), row = m*16 + (l>>4)*4 + j
    float w20[4], w21[4], b1v[4];
    #pragma unroll
    for (int n = 0; n < 4; n++) {
        int cc = (((w << 2) + n) << 4) + frow;
        b1v[n] = b1[cc];
        w20[n] = W2[2 * cc];
        w21[n] = W2[2 * cc + 1];
    }
    float ps0[2][4], ps1[2][4], embp[4] = {0.f, 0.f, 0.f, 0.f};
    #pragma unroll
    for (int m = 0; m < 2; m++)
        #pragma unroll
        for (int j = 0; j < 4; j++) { ps0[m][j] = 0.f; ps1[m][j] = 0.f; }

    #pragma unroll
    for (int m = 0; m < 2; m++)
        #pragma unroll
        for (int n = 0; n < 4; n++)
            #pragma unroll
            for (int j = 0; j < 4; j++) {
                float h = fmaxf(acc[m][n][j] + b1v[n], 0.f);
                ps0[m][j] += h * w20[n];
                ps1[m][j] += h * w21[n];
                int row = (m << 4) + (fk << 2) + j;
                if (row < vr) embp[n] += h;      // exclude pad rows
            }

    #pragma unroll
    for (int off = 1; off < 16; off <<= 1)
        #pragma unroll
        for (int m = 0; m < 2; m++)
            #pragma unroll
            for (int j = 0; j < 4; j++) {
                ps0[m][j] += __shfl_xor(ps0[m][j], off);
                ps1[m][j] += __shfl_xor(ps1[m][j], off);
            }
    if (frow == 0) {
        #pragma unroll
        for (int m = 0; m < 2; m++)
            #pragma unroll
            for (int j = 0; j < 4; j++) {
                int row = (m << 4) + (fk << 2) + j;
                red0[w][row] = ps0[m][j];
                red1[w][row] = ps1[m][j];
            }
    }

    #pragma unroll
    for (int n = 0; n < 4; n++) {
        embp[n] += __shfl_xor(embp[n], 16);
        embp[n] += __shfl_xor(embp[n], 32);
    }
    if (l < 16) {
        #pragma unroll
        for (int n = 0; n < 4; n++)
            atomicAdd(emb + (size_t)batch * 256 + (((w << 2) + n) << 4) + l, embp[n]);
    }

    __syncthreads();   // the ONLY block barrier
    if (t < vr) {
        float v0 = b2[0] + red0[0][t] + red0[1][t] + red0[2][t] + red0[3][t];
        float v1 = b2[1] + red1[0][t] + red1[1][t] + red1[2][t] + red1[3][t];
        Dreg[row0 + t] = v0;    // raw e2 ch0 (symmetrized in recon)
        Wreg[row0 + t] = v1;
    }
}

// ---------------------------------------------------------------------------
// Kernel 2 (unchanged from R11): sym+softplus + register MDS recon, split-q
// across lane halves, LDS same-address broadcasts, readlane-free.
// ---------------------------------------------------------------------------
__global__ __launch_bounds__(64) void symrecon_kernel(
    float* __restrict__ Dreg, float* __restrict__ Wreg,
    const float* __restrict__ un, const float* __restrict__ xn,
    float* __restrict__ Xo)
{
    const int b = blockIdx.x, l = threadIdx.x;
    __shared__ float R0[NN], R1[NN];
    __shared__ float Rs[22], Us[22], Xs[3][22];

    float* Db = Dreg + (size_t)b * NN;
    float* Wb = Wreg + (size_t)b * NN;
    for (int idx = l; idx < NN; idx += 64) { R0[idx] = Db[idx]; R1[idx] = Wb[idx]; }
    if (l == 0) { Rs[21] = 0.f; Us[21] = 0.f; Xs[0][21] = 0.f; Xs[1][21] = 0.f; Xs[2][21] = 0.f; }
    __syncthreads();

    const int half = l >> 5;          // 0: q 0..10, 1: q 11..20 (+pad 21)
    const int li   = l & 31;          // point index
    const bool act = li < NMAX;
    const int li0  = act ? li : 0;
    const int q0   = half * 11;

    // ---- symmetrize + softplus, half-row per lane ----
    float Drow[11], Wrow[11], WD[11];
    float rsh = 0.f;
    #pragma unroll
    for (int j = 0; j < 11; j++) {
        int q = q0 + j;
        bool v = act && (q < NMAX);
        int qc = v ? q : 0;
        float rd = R0[li0 * NMAX + qc] + R0[qc * NMAX + li0];
        float rw = R1[li0 * NMAX + qc] + R1[qc * NMAX + li0];
        float d  = (v && q != li) ? softplus_fast(rd) : 0.f;
        float wv = v ? softplus_fast(rw) : 0.f;
        Drow[j] = d; Wrow[j] = wv; WD[j] = wv * d;
        rsh += d;
    }
    if (act) {
        #pragma unroll
        for (int j = 0; j < 11; j++) {
            int q = q0 + j;
            if (q < NMAX) {
                Db[li * NMAX + q] = Drow[j];
                Wb[li * NMAX + q] = Wrow[j];
            }
        }
    }

    // ---- double-centering ----
    float rsf = rsh + __shfl_xor(rsh, 32);   // full row sum for point li
    float tot = rsh;
    #pragma unroll
    for (int m = 1; m < 64; m <<= 1) tot += __shfl_xor(tot, m);
    const float mean = tot * (1.f / (float)NN);
    const float rsn  = rsf * (1.f / (float)NMAX);
    if (act && half == 0) Rs[li] = rsn;      // broadcast table (wave-ordered)
    float Arow[11];
    #pragma unroll
    for (int j = 0; j < 11; j++) {
        int q = q0 + j;
        bool v = act && (q < NMAX);
        float rsq = Rs[q];                   // LDS broadcast (pad q=21 -> 0)
        Arow[j] = v ? -0.5f * (Drow[j] - rsn - rsq + mean) : 0.f;
    }

    // ---- deflated power iteration: k=3 eigvecs, 10 steps each ----
    float xc[3];
    #pragma unroll
    for (int e = 0; e < 3; e++) {
        float u = act ? un[(size_t)b * 63 + e * NMAX + li] : 0.f;
        for (int s = 0; s < 10; s++) {
            float n2 = (act && half == 0) ? u * u : 0.f;
            #pragma unroll
            for (int m = 1; m < 64; m <<= 1) n2 += __shfl_xor(n2, m);
            u *= fminf(__builtin_amdgcn_rsqf(n2), 1000.f);
            if (act && half == 0) Us[li] = u;
            float a = 0.f;
            #pragma unroll
            for (int j = 0; j < 11; j++) a = fmaf(Arow[j], Us[q0 + j], a);
            a += __shfl_xor(a, 32);
            u = act ? a : 0.f;
        }
        float e2 = (act && half == 0) ? u * u : 0.f;
        #pragma unroll
        for (int m = 1; m < 64; m <<= 1) e2 += __shfl_xor(e2, m);
        u *= sqrtf(__builtin_amdgcn_rsqf(e2 + 0.01f));   // (e2+.01)^-0.25
        xc[e] = u;
        if (act && half == 0) Us[li] = u;
        #pragma unroll
        for (int j = 0; j < 11; j++) Arow[j] = fmaf(-u, Us[q0 + j], Arow[j]);
    }
    float x = xc[0], y = xc[1], z = xc[2];
    if (act) {
        x += xn[(size_t)b * 63 + li * 3 + 0];
        y += xn[(size_t)b * 63 + li * 3 + 1];
        z += xn[(size_t)b * 63 + li * 3 + 2];
    }
    if (act && half == 0) { Xs[0][li] = x; Xs[1][li] = y; Xs[2][li] = z; }

    // ---- 100 clipped GD steps: half-q per lane, LDS X broadcasts ----
    for (int tstep = 0; tstep < 100; tstep++) {
        float gx = 0.f, gy = 0.f, gz = 0.f;
        #pragma unroll
        for (int j = 0; j < 11; j++) {
            int q = q0 + j;
            float dx = x - Xs[0][q];
            float dy = y - Xs[1][q];
            float dz = z - Xs[2][q];
            float s  = fmaf(dx, dx, fmaf(dy, dy, fmaf(dz, dz, 0.01f)));
            float cm = fmaf(-Wrow[j], s, WD[j]);   // W*(D - s), pad -> 0
            gx = fmaf(cm, dx, gx);
            gy = fmaf(cm, dy, gy);
            gz = fmaf(cm, dz, gz);
        }
        gx += __shfl_xor(gx, 32);
        gy += __shfl_xor(gy, 32);
        gz += __shfl_xor(gz, 32);
        float d0 = 0.8f * gx, d1 = 0.8f * gy, d2 = 0.8f * gz;
        float ss = fmaf(d0, d0, fmaf(d1, d1, fmaf(d2, d2, 1e-3f)));
        float inv_sp = __builtin_amdgcn_rsqf(ss);
        float speed  = ss * inv_sp;
        float alpha  = fmaf(-0.049f, (float)tstep, 5.0f);
        float th     = tanh_fast(speed * __builtin_amdgcn_rcpf(alpha));
        float scale  = alpha * th * inv_sp;
        x = fmaf(d0, scale, x);
        y = fmaf(d1, scale, y);
        z = fmaf(d2, scale, z);
        if (act && half == 0) { Xs[0][li] = x; Xs[1][li] = y; Xs[2][li] = z; }
    }
    if (act && half == 0) {
        Xo[(size_t)b * 63 + li * 3 + 0] = x;
        Xo[(size_t)b * 63 + li * 3 + 1] = y;
        Xo[(size_t)b * 63 + li * 3 + 2] = z;
    }
}

// ---------------------------------------------------------------------------
extern "C" void kernel_launch(void* const* d_in, const int* in_sizes, int n_in,
                              void* d_out, int out_size, void* d_ws, size_t ws_size,
                              hipStream_t stream) {
    const float* gnn = (const float*)d_in[0];
    const float* W1  = (const float*)d_in[1];
    const float* b1  = (const float*)d_in[2];
    const float* W2  = (const float*)d_in[3];
    const float* b2  = (const float*)d_in[4];
    const float* un  = (const float*)d_in[5];
    const float* xn  = (const float*)d_in[6];

    float* out  = (float*)d_out;
    float* Dreg = out;                                  // [1024*441]
    float* Wreg = out + (size_t)TOT_ROWS;               // [1024*441]
    float* emb  = out + (size_t)2 * TOT_ROWS;           // [1024*256]
    float* Xo   = out + (size_t)2 * TOT_ROWS + B_SZ*256;// [1024*63]

    short* B0p = (short*)d_ws;                          // 65536 bf16 (128KB)

    pack_w1<<<dim3(256), dim3(256), 0, stream>>>(W1, B0p, emb);

    fused_mlp_bf16<<<dim3(B_SZ * TILES_PB), dim3(256), 0, stream>>>(
        gnn, B0p, b1, W2, b2, Dreg, Wreg, emb);

    symrecon_kernel<<<dim3(B_SZ), dim3(64), 0, stream>>>(Dreg, Wreg, un, xn, Xo);
}

// Round 17
// 251.897 us; speedup vs baseline: 1.4883x; 1.4883x over previous
//
#include <hip/hip_runtime.h>
#include <hip/hip_bf16.h>
#include <math.h>

#define B_SZ 1024
#define NMAX 21
#define NN 441            // 21*21
#define HNF 256
#define TOT_ROWS (B_SZ * NN)   // 451584
#define TILES_PB 14            // 14 tiles of 32 rows per batch (448 >= 441)
#define TROWS 32

typedef short short8 __attribute__((ext_vector_type(8)));
typedef float float4v __attribute__((ext_vector_type(4)));

__device__ __forceinline__ unsigned short f2bf(float x) {
    union { float f; unsigned int u; } v; v.f = x;
    unsigned int r = v.u + 0x7FFFu + ((v.u >> 16) & 1u);   // RNE
    return (unsigned short)(r >> 16);
}

// hardware packed fp32->bf16 (v_cvt_pk_bf16_f32), RNE
__device__ __forceinline__ unsigned pk_bf16(float lo, float hi) {
    __hip_bfloat162 h = __float22bfloat162_rn(float2{lo, hi});
    return *reinterpret_cast<unsigned*>(&h);
}

// fast softplus: max(x,0) + ln2*log2(1 + exp2(-|x|*log2e)), raw v_exp/v_log
__device__ __forceinline__ float softplus_fast(float x) {
    float e = __builtin_amdgcn_exp2f(-fabsf(x) * 1.44269504088896f);
    float lg = __builtin_amdgcn_logf(1.f + e);
    return fmaxf(x, 0.f) + 0.69314718055995f * lg;
}

// fast tanh for x>=0: 1 - 2/(exp2(x*2log2e)+1). v_exp/v_rcp approx (~1e-7).
__device__ __forceinline__ float tanh_fast(float x) {
    float e = __builtin_amdgcn_exp2f(x * 2.8853900817779268f);
    float q = __builtin_amdgcn_rcpf(e + 1.f);
    return fmaf(-2.f, q, 1.f);
}

// ---------------------------------------------------------------------------
// Pack W1 into MFMA B-fragment order as bf16 (+ zero emb, folded in).
// ---------------------------------------------------------------------------
__global__ __launch_bounds__(256) void pack_w1(const float* __restrict__ W1,
                                               short* __restrict__ B0p,
                                               float* __restrict__ emb)
{
    int id = blockIdx.x * 256 + threadIdx.x;   // 0..65535
    int j = id & 7, l = (id >> 3) & 63, f = (id >> 9) & 15, s = id >> 13;
    int k = s * 32 + ((l >> 4) << 3) + j;
    int c = (f << 4) + (l & 15);
    B0p[id] = (short)f2bf(W1[k * HNF + c]);
    #pragma unroll
    for (int e = 0; e < 4; e++)
        emb[(size_t)e * 65536 + id] = 0.f;     // 4*65536 = 1024*256
}

// ---------------------------------------------------------------------------
// Kernel 1 (R17): DUAL-PATH TILE PAIR. 7168 blocks x 256 threads (4 waves);
// block = batch bid/7, tiles {2p, 2p+1} (p = bid%7). Tile A (even, always 32
// valid rows) is staged via global_load_lds DMA (R15 path); tile B (odd;
// tile 13 has 25 valid rows) is loaded into REGISTERS (8 x float4/thread)
// issued immediately after the DMA, pinned by an asm memory barrier so the
// compiler cannot sink them. All 16 loads are in flight before tile A's
// compute: vmcnt(12)/vmcnt(8) gates tile A's convert (oldest = DMA),
// vmcnt(0) gates tile B after tile A's compute covered the latency -> HBM
// stays busy through ~70% of the block round. LDS = exactly 32KB (stage +
// 16KB Abf overlay + red overlay at bytes 16384..17407, R15-proven) ->
// 4 blocks/CU at __launch_bounds__(256,4) (VGPR cap 128, need ~112).
// ---------------------------------------------------------------------------
__global__ __launch_bounds__(256, 4) void fused_mlp_bf16(
    const float* __restrict__ gnn, const short* __restrict__ B0p,
    const float* __restrict__ b1, const float* __restrict__ W2,
    const float* __restrict__ b2,
    float* __restrict__ Dreg, float* __restrict__ Wreg, float* __restrict__ emb)
{
    __shared__ __align__(16) char ldsbuf[32768];
    float* stage = (float*)ldsbuf;     // [32][256] fp32, linear
    short* Abf   = (short*)ldsbuf;     // 16KB frag-linear bf16 overlay
    float (*red0)[32] = (float(*)[32])(ldsbuf + 16384);        // overlay
    float (*red1)[32] = (float(*)[32])(ldsbuf + 16384 + 512);  // rows 16-17

    const int t = threadIdx.x;
    const int w = t >> 6, l = t & 63;
    const int batch = blockIdx.x / 7;
    const int pair  = blockIdx.x % 7;
    const int tileA = pair * 2;               // always 32 valid rows
    const int tileB = pair * 2 + 1;           // tile 13 -> 25 valid rows
    const long rowA = (long)batch * NN + (long)tileA * TROWS;
    const long rowB = (long)batch * NN + (long)tileB * TROWS;
    const int vrB = (tileB == TILES_PB - 1) ? (NN - (TILES_PB - 1) * TROWS) : TROWS;

    // staging/convert decode (constant)
    const int kk_s = l >> 3;
    const int fk_s = (l >> 1) & 3;
    const int jh_s = l & 1;
    const int frow = l & 15;
    const int fk   = l >> 4;

    // ---- issue tile A DMA (8 x 1KB rows per wave, linear lanes) ----
    #pragma unroll
    for (int i = 0; i < 8; i++) {
        int r = (w << 3) + i;
        long ar = rowA + r;                            // tile A always valid
        const float* gsrc = gnn + ar * HNF + (l << 2);
        __builtin_amdgcn_global_load_lds(
            (const __attribute__((address_space(1))) unsigned*)gsrc,
            (__attribute__((address_space(3))) unsigned*)(stage + (r << 8)),
            16, 0, 0);
    }
    // ---- issue tile B register loads (same lane mapping, to VGPRs) ----
    float4 fb[8];
    #pragma unroll
    for (int i = 0; i < 8; i++) {
        long ar = rowB + (w << 3) + i;
        if (ar >= (long)TOT_ROWS) ar = TOT_ROWS - 1;   // tail clamp
        fb[i] = *(const float4*)(gnn + ar * HNF + (l << 2));
    }
    asm volatile("" ::: "memory");    // pin: reg loads may not sink below here

    // invariant epilogue weights (scalar loads, don't disturb vmcnt order
    // materially; s_load goes through lgkmcnt)
    float w20[4], w21[4], b1v[4];
    #pragma unroll
    for (int n = 0; n < 4; n++) {
        int cc = (((w << 2) + n) << 4) + frow;
        b1v[n] = b1[cc];
        w20[n] = W2[2 * cc];
        w21[n] = W2[2 * cc + 1];
    }

    // ================== TILE A (DMA path) ==================
    uint2 pv[8];
    asm volatile("s_waitcnt vmcnt(12)" ::: "memory");  // DMA rows 0..3 landed
    #pragma unroll
    for (int i = 0; i < 4; i++) {
        float4 f = *(const float4*)(stage + (((w << 3) + i) << 8) + (l << 2));
        pv[i].x = pk_bf16(f.x, f.y);
        pv[i].y = pk_bf16(f.z, f.w);
    }
    asm volatile("s_waitcnt vmcnt(8)" ::: "memory");   // DMA rows 4..7 landed
    #pragma unroll
    for (int i = 4; i < 8; i++) {
        float4 f = *(const float4*)(stage + (((w << 3) + i) << 8) + (l << 2));
        pv[i].x = pk_bf16(f.x, f.y);
        pv[i].y = pk_bf16(f.z, f.w);
    }
    __syncthreads();   // all stage reads done before Abf overlay
    #pragma unroll
    for (int i = 0; i < 8; i++) {
        int r = (w << 3) + i;
        int di = (((kk_s << 1) + (r >> 4)) << 6) | (fk_s << 4) | (r & 15);
        *(uint2*)((char*)Abf + (((size_t)(di ^ kk_s)) << 4) + (jh_s << 3)) = pv[i];
    }
    __syncthreads();   // Abf visible

    float4v acc[2][4];
    #pragma unroll
    for (int m = 0; m < 2; m++)
        #pragma unroll
        for (int n = 0; n < 4; n++)
            acc[m][n] = (float4v){0.f, 0.f, 0.f, 0.f};

    #pragma unroll 2
    for (int kk = 0; kk < 8; ++kk) {
        short8 bf[4], af[2];
        #pragma unroll
        for (int n = 0; n < 4; n++) {
            int nf = (w << 2) + n;
            size_t off = (size_t)((((kk << 4) + nf) << 6) | l) << 3;
            bf[n] = *(const short8*)(B0p + off);
        }
        #pragma unroll
        for (int m = 0; m < 2; m++) {
            int di = ((((kk << 1) + m) << 6) | l) ^ kk;
            af[m] = *(const short8*)(Abf + (size_t)di * 8);
        }
        #pragma unroll
        for (int m = 0; m < 2; m++)
            #pragma unroll
            for (int n = 0; n < 4; n++)
                acc[m][n] = __builtin_amdgcn_mfma_f32_16x16x32_bf16(af[m], bf[n], acc[m][n], 0, 0, 0);
    }

    float embp[4] = {0.f, 0.f, 0.f, 0.f};
    {
        float ps0[2][4], ps1[2][4];
        #pragma unroll
        for (int m = 0; m < 2; m++)
            #pragma unroll
            for (int j = 0; j < 4; j++) { ps0[m][j] = 0.f; ps1[m][j] = 0.f; }
        #pragma unroll
        for (int m = 0; m < 2; m++)
            #pragma unroll
            for (int n = 0; n < 4; n++)
                #pragma unroll
                for (int j = 0; j < 4; j++) {
                    float h = fmaxf(acc[m][n][j] + b1v[n], 0.f);
                    ps0[m][j] += h * w20[n];
                    ps1[m][j] += h * w21[n];
                    embp[n] += h;                     // tile A: all 32 valid
                }
        #pragma unroll
        for (int off = 1; off < 16; off <<= 1)
            #pragma unroll
            for (int m = 0; m < 2; m++)
                #pragma unroll
                for (int j = 0; j < 4; j++) {
                    ps0[m][j] += __shfl_xor(ps0[m][j], off);
                    ps1[m][j] += __shfl_xor(ps1[m][j], off);
                }
        if (frow == 0) {
            #pragma unroll
            for (int m = 0; m < 2; m++)
                #pragma unroll
                for (int j = 0; j < 4; j++) {
                    int row = (m << 4) + (fk << 2) + j;
                    red0[w][row] = ps0[m][j];
                    red1[w][row] = ps1[m][j];
                }
        }
        __syncthreads();   // red ready; all Abf reads of tile A done
        if (t < TROWS) {
            float v0 = b2[0] + red0[0][t] + red0[1][t] + red0[2][t] + red0[3][t];
            float v1 = b2[1] + red1[0][t] + red1[1][t] + red1[2][t] + red1[3][t];
            Dreg[rowA + t] = v0;
            Wreg[rowA + t] = v1;
        }
    }

    // ================== TILE B (register path) ==================
    asm volatile("s_waitcnt vmcnt(0)" ::: "memory");   // reg loads landed
    #pragma unroll
    for (int i = 0; i < 8; i++) {
        pv[i].x = pk_bf16(fb[i].x, fb[i].y);
        pv[i].y = pk_bf16(fb[i].z, fb[i].w);
    }
    // safe to overwrite Abf: last barrier was after all tile-A Abf reads
    #pragma unroll
    for (int i = 0; i < 8; i++) {
        int r = (w << 3) + i;
        int di = (((kk_s << 1) + (r >> 4)) << 6) | (fk_s << 4) | (r & 15);
        *(uint2*)((char*)Abf + (((size_t)(di ^ kk_s)) << 4) + (jh_s << 3)) = pv[i];
    }
    __syncthreads();   // Abf (tile B) visible; also orders red A-reads before B-writes

    #pragma unroll
    for (int m = 0; m < 2; m++)
        #pragma unroll
        for (int n = 0; n < 4; n++)
            acc[m][n] = (float4v){0.f, 0.f, 0.f, 0.f};

    #pragma unroll 2
    for (int kk = 0; kk < 8; ++kk) {
        short8 bf[4], af[2];
        #pragma unroll
        for (int n = 0; n < 4; n++) {
            int nf = (w << 2) + n;
            size_t off = (size_t)((((kk << 4) + nf) << 6) | l) << 3;
            bf[n] = *(const short8*)(B0p + off);
        }
        #pragma unroll
        for (int m = 0; m < 2; m++) {
            int di = ((((kk << 1) + m) << 6) | l) ^ kk;
            af[m] = *(const short8*)(Abf + (size_t)di * 8);
        }
        #pragma unroll
        for (int m = 0; m < 2; m++)
            #pragma unroll
            for (int n = 0; n < 4; n++)
                acc[m][n] = __builtin_amdgcn_mfma_f32_16x16x32_bf16(af[m], bf[n], acc[m][n], 0, 0, 0);
    }

    {
        float ps0[2][4], ps1[2][4];
        #pragma unroll
        for (int m = 0; m < 2; m++)
            #pragma unroll
            for (int j = 0; j < 4; j++) { ps0[m][j] = 0.f; ps1[m][j] = 0.f; }
        #pragma unroll
        for (int m = 0; m < 2; m++)
            #pragma unroll
            for (int n = 0; n < 4; n++)
                #pragma unroll
                for (int j = 0; j < 4; j++) {
                    float h = fmaxf(acc[m][n][j] + b1v[n], 0.f);
                    ps0[m][j] += h * w20[n];
                    ps1[m][j] += h * w21[n];
                    int row = (m << 4) + (fk << 2) + j;
                    if (row < vrB) embp[n] += h;      // exclude tail pad rows
                }
        #pragma unroll
        for (int off = 1; off < 16; off <<= 1)
            #pragma unroll
            for (int m = 0; m < 2; m++)
                #pragma unroll
                for (int j = 0; j < 4; j++) {
                    ps0[m][j] += __shfl_xor(ps0[m][j], off);
                    ps1[m][j] += __shfl_xor(ps1[m][j], off);
                }
        __syncthreads();   // tile A's red reads complete (defensive; cheap)
        if (frow == 0) {
            #pragma unroll
            for (int m = 0; m < 2; m++)
                #pragma unroll
                for (int j = 0; j < 4; j++) {
                    int row = (m << 4) + (fk << 2) + j;
                    red0[w][row] = ps0[m][j];
                    red1[w][row] = ps1[m][j];
                }
        }
        __syncthreads();
        if (t < vrB) {
            float v0 = b2[0] + red0[0][t] + red0[1][t] + red0[2][t] + red0[3][t];
            float v1 = b2[1] + red1[0][t] + red1[1][t] + red1[2][t] + red1[3][t];
            Dreg[rowB + t] = v0;
            Wreg[rowB + t] = v1;
        }
    }

    // ---- emb: one reduce + one atomic per thread for both tiles ----
    #pragma unroll
    for (int n = 0; n < 4; n++) {
        embp[n] += __shfl_xor(embp[n], 16);
        embp[n] += __shfl_xor(embp[n], 32);
    }
    if (l < 16) {
        #pragma unroll
        for (int n = 0; n < 4; n++)
            atomicAdd(emb + (size_t)batch * 256 + (((w << 2) + n) << 4) + l, embp[n]);
    }
}

// ---------------------------------------------------------------------------
// Kernel 2 (unchanged from R11): sym+softplus + register MDS recon, split-q
// across lane halves, LDS same-address broadcasts, readlane-free.
// ---------------------------------------------------------------------------
__global__ __launch_bounds__(64) void symrecon_kernel(
    float* __restrict__ Dreg, float* __restrict__ Wreg,
    const float* __restrict__ un, const float* __restrict__ xn,
    float* __restrict__ Xo)
{
    const int b = blockIdx.x, l = threadIdx.x;
    __shared__ float R0[NN], R1[NN];
    __shared__ float Rs[22], Us[22], Xs[3][22];

    float* Db = Dreg + (size_t)b * NN;
    float* Wb = Wreg + (size_t)b * NN;
    for (int idx = l; idx < NN; idx += 64) { R0[idx] = Db[idx]; R1[idx] = Wb[idx]; }
    if (l == 0) { Rs[21] = 0.f; Us[21] = 0.f; Xs[0][21] = 0.f; Xs[1][21] = 0.f; Xs[2][21] = 0.f; }
    __syncthreads();

    const int half = l >> 5;          // 0: q 0..10, 1: q 11..20 (+pad 21)
    const int li   = l & 31;          // point index
    const bool act = li < NMAX;
    const int li0  = act ? li : 0;
    const int q0   = half * 11;

    float Drow[11], Wrow[11], WD[11];
    float rsh = 0.f;
    #pragma unroll
    for (int j = 0; j < 11; j++) {
        int q = q0 + j;
        bool v = act && (q < NMAX);
        int qc = v ? q : 0;
        float rd = R0[li0 * NMAX + qc] + R0[qc * NMAX + li0];
        float rw = R1[li0 * NMAX + qc] + R1[qc * NMAX + li0];
        float d  = (v && q != li) ? softplus_fast(rd) : 0.f;
        float wv = v ? softplus_fast(rw) : 0.f;
        Drow[j] = d; Wrow[j] = wv; WD[j] = wv * d;
        rsh += d;
    }
    if (act) {
        #pragma unroll
        for (int j = 0; j < 11; j++) {
            int q = q0 + j;
            if (q < NMAX) {
                Db[li * NMAX + q] = Drow[j];
                Wb[li * NMAX + q] = Wrow[j];
            }
        }
    }

    float rsf = rsh + __shfl_xor(rsh, 32);
    float tot = rsh;
    #pragma unroll
    for (int m = 1; m < 64; m <<= 1) tot += __shfl_xor(tot, m);
    const float mean = tot * (1.f / (float)NN);
    const float rsn  = rsf * (1.f / (float)NMAX);
    if (act && half == 0) Rs[li] = rsn;
    float Arow[11];
    #pragma unroll
    for (int j = 0; j < 11; j++) {
        int q = q0 + j;
        bool v = act && (q < NMAX);
        float rsq = Rs[q];
        Arow[j] = v ? -0.5f * (Drow[j] - rsn - rsq + mean) : 0.f;
    }

    float xc[3];
    #pragma unroll
    for (int e = 0; e < 3; e++) {
        float u = act ? un[(size_t)b * 63 + e * NMAX + li] : 0.f;
        for (int s = 0; s < 10; s++) {
            float n2 = (act && half == 0) ? u * u : 0.f;
            #pragma unroll
            for (int m = 1; m < 64; m <<= 1) n2 += __shfl_xor(n2, m);
            u *= fminf(__builtin_amdgcn_rsqf(n2), 1000.f);
            if (act && half == 0) Us[li] = u;
            float a = 0.f;
            #pragma unroll
            for (int j = 0; j < 11; j++) a = fmaf(Arow[j], Us[q0 + j], a);
            a += __shfl_xor(a, 32);
            u = act ? a : 0.f;
        }
        float e2 = (act && half == 0) ? u * u : 0.f;
        #pragma unroll
        for (int m = 1; m < 64; m <<= 1) e2 += __shfl_xor(e2, m);
        u *= sqrtf(__builtin_amdgcn_rsqf(e2 + 0.01f));
        xc[e] = u;
        if (act && half == 0) Us[li] = u;
        #pragma unroll
        for (int j = 0; j < 11; j++) Arow[j] = fmaf(-u, Us[q0 + j], Arow[j]);
    }
    float x = xc[0], y = xc[1], z = xc[2];
    if (act) {
        x += xn[(size_t)b * 63 + li * 3 + 0];
        y += xn[(size_t)b * 63 + li * 3 + 1];
        z += xn[(size_t)b * 63 + li * 3 + 2];
    }
    if (act && half == 0) { Xs[0][li] = x; Xs[1][li] = y; Xs[2][li] = z; }

    for (int tstep = 0; tstep < 100; tstep++) {
        float gx = 0.f, gy = 0.f, gz = 0.f;
        #pragma unroll
        for (int j = 0; j < 11; j++) {
            int q = q0 + j;
            float dx = x - Xs[0][q];
            float dy = y - Xs[1][q];
            float dz = z - Xs[2][q];
            float s  = fmaf(dx, dx, fmaf(dy, dy, fmaf(dz, dz, 0.01f)));
            float cm = fmaf(-Wrow[j], s, WD[j]);
            gx = fmaf(cm, dx, gx);
            gy = fmaf(cm, dy, gy);
            gz = fmaf(cm, dz, gz);
        }
        gx += __shfl_xor(gx, 32);
        gy += __shfl_xor(gy, 32);
        gz += __shfl_xor(gz, 32);
        float d0 = 0.8f * gx, d1 = 0.8f * gy, d2 = 0.8f * gz;
        float ss = fmaf(d0, d0, fmaf(d1, d1, fmaf(d2, d2, 1e-3f)));
        float inv_sp = __builtin_amdgcn_rsqf(ss);
        float speed  = ss * inv_sp;
        float alpha  = fmaf(-0.049f, (float)tstep, 5.0f);
        float th     = tanh_fast(speed * __builtin_amdgcn_rcpf(alpha));
        float scale  = alpha * th * inv_sp;
        x = fmaf(d0, scale, x);
        y = fmaf(d1, scale, y);
        z = fmaf(d2, scale, z);
        if (act && half == 0) { Xs[0][li] = x; Xs[1][li] = y; Xs[2][li] = z; }
    }
    if (act && half == 0) {
        Xo[(size_t)b * 63 + li * 3 + 0] = x;
        Xo[(size_t)b * 63 + li * 3 + 1] = y;
        Xo[(size_t)b * 63 + li * 3 + 2] = z;
    }
}

// ---------------------------------------------------------------------------
extern "C" void kernel_launch(void* const* d_in, const int* in_sizes, int n_in,
                              void* d_out, int out_size, void* d_ws, size_t ws_size,
                              hipStream_t stream) {
    const float* gnn = (const float*)d_in[0];
    const float* W1  = (const float*)d_in[1];
    const float* b1  = (const float*)d_in[2];
    const float* W2  = (const float*)d_in[3];
    const float* b2  = (const float*)d_in[4];
    const float* un  = (const float*)d_in[5];
    const float* xn  = (const float*)d_in[6];

    float* out  = (float*)d_out;
    float* Dreg = out;                                  // [1024*441]
    float* Wreg = out + (size_t)TOT_ROWS;               // [1024*441]
    float* emb  = out + (size_t)2 * TOT_ROWS;           // [1024*256]
    float* Xo   = out + (size_t)2 * TOT_ROWS + B_SZ*256;// [1024*63]

    short* B0p = (short*)d_ws;                          // 65536 bf16 (128KB)

    pack_w1<<<dim3(256), dim3(256), 0, stream>>>(W1, B0p, emb);

    fused_mlp_bf16<<<dim3(B_SZ * 7), dim3(256), 0, stream>>>(
        gnn, B0p, b1, W2, b2, Dreg, Wreg, emb);

    symrecon_kernel<<<dim3(B_SZ), dim3(64), 0, stream>>>(Dreg, Wreg, un, xn, Xo);
}